// Round 1
// baseline (704.226 us; speedup 1.0000x reference)
//
#include <hip/hip_runtime.h>
#include <cstdint>
#include <cstddef>

typedef unsigned short u16;
typedef unsigned int u32;
typedef __attribute__((ext_vector_type(8))) short bf16x8;   // 8 bf16 in 4 VGPRs (per guide §3)
typedef __attribute__((ext_vector_type(4))) float f32x4;

#define MFMA(a, b, c) __builtin_amdgcn_mfma_f32_16x16x32_bf16((a), (b), (c), 0, 0, 0)

#define BATCH 4
#define SEQ 2048
#define DMODEL 1024
#define NHEAD 16
#define MROWS (BATCH * SEQ)   // 8192
#define QKVN (3 * DMODEL)     // 3072

__device__ __forceinline__ u16 f2bf(float f) {
  u32 x = __builtin_bit_cast(u32, f);
  x += 0x7fffu + ((x >> 16) & 1u);   // RNE (values are finite/normal here)
  return (u16)(x >> 16);
}

__device__ __forceinline__ float redmax16(float v) {
  v = fmaxf(v, __shfl_xor(v, 1));
  v = fmaxf(v, __shfl_xor(v, 2));
  v = fmaxf(v, __shfl_xor(v, 4));
  v = fmaxf(v, __shfl_xor(v, 8));
  return v;
}
__device__ __forceinline__ float redsum16(float v) {
  v += __shfl_xor(v, 1);
  v += __shfl_xor(v, 2);
  v += __shfl_xor(v, 4);
  v += __shfl_xor(v, 8);
  return v;
}

// ---------------- fp32 -> bf16 convert of hidden_states ----------------
__global__ __launch_bounds__(256) void convert_h(const float* __restrict__ H,
                                                 u16* __restrict__ Hb) {
  size_t i = (size_t)blockIdx.x * 1024 + threadIdx.x * 4;
  float4 v = *(const float4*)&H[i];
  uint2 o;
  o.x = (u32)f2bf(v.x) | ((u32)f2bf(v.y) << 16);
  o.y = (u32)f2bf(v.z) | ((u32)f2bf(v.w) << 16);
  *(uint2*)&Hb[i] = o;
}

// ------------- transpose + convert Wq|Wk|Wv|Wo -> Wt[4096][1024] -------------
__global__ void transpose_w(const float* __restrict__ Wq, const float* __restrict__ Wk,
                            const float* __restrict__ Wv, const float* __restrict__ Wo,
                            u16* __restrict__ Wt) {
  __shared__ u16 Ts[32][33];
  const float* W = (blockIdx.z == 0) ? Wq : (blockIdx.z == 1) ? Wk
                   : (blockIdx.z == 2) ? Wv : Wo;
  int x = threadIdx.x, y0 = threadIdx.y;
  int r0 = blockIdx.y * 32, c0 = blockIdx.x * 32;
  for (int yy = y0; yy < 32; yy += 8)
    Ts[yy][x] = f2bf(W[(size_t)(r0 + yy) * 1024 + c0 + x]);
  __syncthreads();
  for (int yy = y0; yy < 32; yy += 8)
    Wt[(size_t)(blockIdx.z * 1024 + c0 + yy) * 1024 + r0 + x] = Ts[x][yy];
}

// ---------------- relative-position bucket bias table ----------------
// Exact integer bucketing (boundaries 8*2^(i/2); integer thresholds below).
__device__ __forceinline__ int rel_bucket(int rel) {  // rel = k - q
  int ret = (rel > 0) ? 16 : 0;
  int rp = (rel < 0) ? -rel : rel;
  if (rp < 8) return ret + rp;
  int i = 0;
  i += (rp >= 12); i += (rp >= 16); i += (rp >= 23); i += (rp >= 32);
  i += (rp >= 46); i += (rp >= 64); i += (rp >= 91);
  return ret + 8 + i;
}

__global__ __launch_bounds__(256) void build_bias_rel(const float* __restrict__ tbl,
                                                      float* __restrict__ brel) {
  int h = blockIdx.x;
  for (int rix = threadIdx.x; rix < 4095; rix += 256) {
    int rel = rix - 2047;
    brel[h * 4096 + rix] = tbl[rel_bucket(rel) * NHEAD + h];
  }
}

// ---------------- write pos_bias [1,16,2048,2048] ----------------
__global__ __launch_bounds__(256) void write_pos_bias(const float* __restrict__ brel,
                                                      float* __restrict__ pb) {
  int s = blockIdx.x, h = blockIdx.y;
  const float* br = brel + h * 4096 + 2047 - s;
  float* o = pb + ((size_t)h * SEQ + s) * SEQ;
  #pragma unroll
  for (int p = 0; p < 2; ++p) {
    int k = (threadIdx.x + p * 256) * 4;
    float4 v;
    v.x = br[k]; v.y = br[k + 1]; v.z = br[k + 2]; v.w = br[k + 3];
    *(float4*)&o[k] = v;
  }
}

// ---------------- bf16 MFMA GEMM: C[M][N] = A[M][K] @ Bt[N][K]^T ----------------
__global__ __launch_bounds__(256) void gemm_bf16k(const u16* __restrict__ A,
                                                  const u16* __restrict__ Bt,
                                                  u16* __restrict__ Cb, float* __restrict__ Cf,
                                                  int M, int N, int K) {
  __shared__ u16 As[128 * 32];
  __shared__ u16 Bs[128 * 32];
  const int t = threadIdx.x;
  const int w = t >> 6, lane = t & 63, quad = lane >> 4, l15 = lane & 15;
  const int wr = w >> 1, wc = w & 1;
  const int row0 = blockIdx.y * 128, col0 = blockIdx.x * 128;

  f32x4 acc[4][4];
  #pragma unroll
  for (int i = 0; i < 4; ++i)
    #pragma unroll
    for (int j = 0; j < 4; ++j) acc[i][j] = (f32x4){0.f, 0.f, 0.f, 0.f};

  const int c0 = t * 2, c1 = t * 2 + 1;
  const int ar0 = c0 >> 2, ac0 = (c0 & 3) * 8;
  const int ar1 = c1 >> 2, ac1 = (c1 & 3) * 8;

  for (int k0 = 0; k0 < K; k0 += 32) {
    *(uint4*)&As[ar0 * 32 + ac0] = *(const uint4*)&A[(size_t)(row0 + ar0) * K + k0 + ac0];
    *(uint4*)&As[ar1 * 32 + ac1] = *(const uint4*)&A[(size_t)(row0 + ar1) * K + k0 + ac1];
    *(uint4*)&Bs[ar0 * 32 + ac0] = *(const uint4*)&Bt[(size_t)(col0 + ar0) * K + k0 + ac0];
    *(uint4*)&Bs[ar1 * 32 + ac1] = *(const uint4*)&Bt[(size_t)(col0 + ar1) * K + k0 + ac1];
    __syncthreads();
    bf16x8 af[4], bfr[4];
    #pragma unroll
    for (int i = 0; i < 4; ++i)
      af[i] = *(const bf16x8*)&As[(wr * 64 + i * 16 + l15) * 32 + quad * 8];
    #pragma unroll
    for (int j = 0; j < 4; ++j)
      bfr[j] = *(const bf16x8*)&Bs[(wc * 64 + j * 16 + l15) * 32 + quad * 8];
    #pragma unroll
    for (int i = 0; i < 4; ++i)
      #pragma unroll
      for (int j = 0; j < 4; ++j)
        acc[i][j] = MFMA(af[i], bfr[j], acc[i][j]);
    __syncthreads();
  }
  #pragma unroll
  for (int i = 0; i < 4; ++i) {
    #pragma unroll
    for (int j = 0; j < 4; ++j) {
      int col = col0 + wc * 64 + j * 16 + l15;
      #pragma unroll
      for (int r = 0; r < 4; ++r) {
        int row = row0 + wr * 64 + i * 16 + quad * 4 + r;
        if (Cb) Cb[(size_t)row * N + col] = f2bf(acc[i][j][r]);
        else    Cf[(size_t)row * N + col] = acc[i][j][r];
      }
    }
  }
}

// ---------------- V -> Vt[bh*64 + d][s] (bf16) ----------------
__global__ __launch_bounds__(256) void transpose_v(const u16* __restrict__ QKV,
                                                   u16* __restrict__ Vt) {
  __shared__ u16 Ts[64 * 72];
  int st = blockIdx.x, bh = blockIdx.y;
  int b = bh >> 4, h = bh & 15;
  int t = threadIdx.x;
  #pragma unroll
  for (int p = 0; p < 2; ++p) {
    int c = t * 2 + p, r = c >> 3, cc = (c & 7) * 8;
    *(uint4*)&Ts[r * 72 + cc] =
        *(const uint4*)&QKV[(size_t)(b * SEQ + st * 64 + r) * QKVN + 2 * DMODEL + h * 64 + cc];
  }
  __syncthreads();
  #pragma unroll
  for (int p = 0; p < 2; ++p) {
    int c = t * 2 + p, d = c >> 3, s8 = (c & 7) * 8;
    union { u16 u[8]; uint4 v; } tmp;
    #pragma unroll
    for (int jj = 0; jj < 8; ++jj) tmp.u[jj] = Ts[(s8 + jj) * 72 + d];
    *(uint4*)&Vt[((size_t)(bh * 64 + d)) * SEQ + st * 64 + s8] = tmp.v;
  }
}

// ---------------- fused flash attention ----------------
__global__ __launch_bounds__(256) void attn_fused(const u16* __restrict__ QKV,
                                                  const u16* __restrict__ Vt,
                                                  const float* __restrict__ brel,
                                                  u16* __restrict__ Aout) {
  __shared__ u16 Ks[64 * 72];
  __shared__ u16 Vs[64 * 72];
  __shared__ u16 Ps[4 * 16 * 72];
  const int qt = blockIdx.x, bh = blockIdx.y;
  const int b = bh >> 4, h = bh & 15;
  const int t = threadIdx.x;
  const int w = t >> 6, lane = t & 63, quad = lane >> 4, l15 = lane & 15;
  const int qb = qt * 64;

  // Q fragments (held for the whole k-loop), A-layout: m=l15 row, k=d
  const u16* qptr = QKV + (size_t)(b * SEQ + qb + w * 16 + l15) * QKVN + h * 64 + quad * 8;
  bf16x8 aq0 = *(const bf16x8*)qptr;
  bf16x8 aq1 = *(const bf16x8*)(qptr + 32);

  float mrow[4] = {-1e30f, -1e30f, -1e30f, -1e30f};
  float lrow[4] = {0.f, 0.f, 0.f, 0.f};
  f32x4 oacc[4];
  #pragma unroll
  for (int j = 0; j < 4; ++j) oacc[j] = (f32x4){0.f, 0.f, 0.f, 0.f};

  const int c0 = t * 2, c1 = c0 + 1;
  const int r0s = c0 >> 3, cc0 = (c0 & 7) * 8;
  const int r1s = c1 >> 3, cc1 = (c1 & 7) * 8;
  const size_t krow = (size_t)(b * SEQ) * QKVN + DMODEL + h * 64;
  const size_t vtrow = (size_t)bh * 64;
  const float* brow = brel + h * 4096 + 2047;
  const int dbias = l15 - (qb + w * 16 + quad * 4);  // + kb + j*16 - r
  u16* Pw = &Ps[w * 16 * 72];

  for (int kb = 0; kb < SEQ; kb += 64) {
    *(uint4*)&Ks[r0s * 72 + cc0] = *(const uint4*)&QKV[krow + (size_t)(kb + r0s) * QKVN + cc0];
    *(uint4*)&Ks[r1s * 72 + cc1] = *(const uint4*)&QKV[krow + (size_t)(kb + r1s) * QKVN + cc1];
    *(uint4*)&Vs[r0s * 72 + cc0] = *(const uint4*)&Vt[(vtrow + r0s) * SEQ + kb + cc0];
    *(uint4*)&Vs[r1s * 72 + cc1] = *(const uint4*)&Vt[(vtrow + r1s) * SEQ + kb + cc1];
    __syncthreads();

    // S = Q @ K^T  (B-operand: n=kpos=l15-row of Ks, k=d)
    f32x4 sc[4];
    #pragma unroll
    for (int j = 0; j < 4; ++j) {
      bf16x8 bk0 = *(const bf16x8*)&Ks[(j * 16 + l15) * 72 + quad * 8];
      bf16x8 bk1 = *(const bf16x8*)&Ks[(j * 16 + l15) * 72 + 32 + quad * 8];
      f32x4 z = (f32x4){0.f, 0.f, 0.f, 0.f};
      z = MFMA(aq0, bk0, z);
      z = MFMA(aq1, bk1, z);
      sc[j] = z;
    }

    // bias + online softmax (rows = quad*4+r, cols = kb + j*16 + l15)
    float pv[4][4];
    float tmax[4] = {-1e30f, -1e30f, -1e30f, -1e30f};
    #pragma unroll
    for (int j = 0; j < 4; ++j)
      #pragma unroll
      for (int r = 0; r < 4; ++r) {
        float s = sc[j][r] + brow[kb + j * 16 + dbias - r];
        pv[j][r] = s;
        tmax[r] = fmaxf(tmax[r], s);
      }
    float alpha[4], rsum[4];
    #pragma unroll
    for (int r = 0; r < 4; ++r) {
      float mn = fmaxf(mrow[r], redmax16(tmax[r]));
      alpha[r] = __expf(mrow[r] - mn);
      mrow[r] = mn;
      rsum[r] = 0.f;
    }
    #pragma unroll
    for (int j = 0; j < 4; ++j)
      #pragma unroll
      for (int r = 0; r < 4; ++r) {
        float p = __expf(pv[j][r] - mrow[r]);
        rsum[r] += p;
        Pw[(quad * 4 + r) * 72 + j * 16 + l15] = f2bf(p);  // C-layout -> LDS
      }
    #pragma unroll
    for (int r = 0; r < 4; ++r)
      lrow[r] = lrow[r] * alpha[r] + redsum16(rsum[r]);
    #pragma unroll
    for (int j = 0; j < 4; ++j) {
      oacc[j][0] *= alpha[0]; oacc[j][1] *= alpha[1];
      oacc[j][2] *= alpha[2]; oacc[j][3] *= alpha[3];
    }
    // make P writes visible to same-wave A-layout reads
    asm volatile("s_waitcnt lgkmcnt(0)" ::: "memory");
    bf16x8 ap0 = *(const bf16x8*)&Pw[l15 * 72 + quad * 8];
    bf16x8 ap1 = *(const bf16x8*)&Pw[l15 * 72 + 32 + quad * 8];
    #pragma unroll
    for (int j = 0; j < 4; ++j) {
      bf16x8 bv0 = *(const bf16x8*)&Vs[(j * 16 + l15) * 72 + quad * 8];
      bf16x8 bv1 = *(const bf16x8*)&Vs[(j * 16 + l15) * 72 + 32 + quad * 8];
      oacc[j] = MFMA(ap0, bv0, oacc[j]);
      oacc[j] = MFMA(ap1, bv1, oacc[j]);
    }
    __syncthreads();
  }

  #pragma unroll
  for (int r = 0; r < 4; ++r) {
    float inv = 1.0f / lrow[r];
    int row = b * SEQ + qb + w * 16 + quad * 4 + r;
    #pragma unroll
    for (int j = 0; j < 4; ++j)
      Aout[(size_t)row * DMODEL + h * 64 + j * 16 + l15] = f2bf(oacc[j][r] * inv);
  }
}

extern "C" void kernel_launch(void* const* d_in, const int* in_sizes, int n_in,
                              void* d_out, int out_size, void* d_ws, size_t ws_size,
                              hipStream_t stream) {
  (void)in_sizes; (void)n_in; (void)out_size; (void)ws_size;
  const float* H   = (const float*)d_in[0];
  const float* Wq  = (const float*)d_in[1];
  const float* Wk  = (const float*)d_in[2];
  const float* Wv  = (const float*)d_in[3];
  const float* Wo  = (const float*)d_in[4];
  const float* tbl = (const float*)d_in[5];

  float* out = (float*)d_out;                       // [8192][1024] fp32
  float* pos_bias = out + (size_t)MROWS * DMODEL;   // [16][2048][2048] fp32

  char* ws = (char*)d_ws;
  u16* Hb    = (u16*)(ws);                 // 16 MB  (reused as attn_out later)
  u16* Wt    = (u16*)(ws + 16777216);      // 8 MB   [4096][1024]
  u16* QKV   = (u16*)(ws + 25165824);      // 48 MB  [8192][3072]
  u16* Vt    = (u16*)(ws + 75497472);      // 16 MB  [4096][2048]
  float* brel = (float*)(ws + 92274688);   // 256 KB [16][4096]

  convert_h<<<8192, 256, 0, stream>>>(H, Hb);
  transpose_w<<<dim3(32, 32, 4), dim3(32, 8), 0, stream>>>(Wq, Wk, Wv, Wo, Wt);
  build_bias_rel<<<16, 256, 0, stream>>>(tbl, brel);
  write_pos_bias<<<dim3(2048, 16), 256, 0, stream>>>(brel, pos_bias);

  // QKV = Hb @ [Wq|Wk|Wv]   (bf16 out)
  gemm_bf16k<<<dim3(QKVN / 128, MROWS / 128), 256, 0, stream>>>(
      Hb, Wt, QKV, nullptr, MROWS, QKVN, DMODEL);
  transpose_v<<<dim3(32, 64), 256, 0, stream>>>(QKV, Vt);
  attn_fused<<<dim3(32, 64), 256, 0, stream>>>(QKV, Vt, brel, Hb /* attn_out */);
  // out = attn_out @ Wo   (fp32 out)
  gemm_bf16k<<<dim3(DMODEL / 128, MROWS / 128), 256, 0, stream>>>(
      Hb, Wt + (size_t)QKVN * DMODEL, nullptr, out, MROWS, DMODEL, DMODEL);
}